// Round 6
// baseline (2126.796 us; speedup 1.0000x reference)
//
#include <hip/hip_runtime.h>
#include <hip/hip_bf16.h>

typedef __bf16 bf16;
typedef __bf16 bf16x8 __attribute__((ext_vector_type(8)));
typedef float f32x4 __attribute__((ext_vector_type(4)));

#define B_SZ 2048
#define L_SZ 200
#define D_SZ 256
#define MT 48            // rows per l-tile (3 m-tiles of 16)
#define NTILE 5          // ceil(200/48)
#define AST 264          // LDS activation row stride in bf16

// workspace offsets in bf16 elements (pre-swizzled bf16 weight fragments)
#define W1F_OFF 0        // w1   256x512 -> 131072
#define W2F_OFF 131072   // w2   256x256 -> 65536
#define A1F_OFF 196608   // att1[:, 0:256] -> 65536
#define A2F_OFF 262144   // att2 256x256 -> 65536

// nontemporal float4 load (keeps streaming gather traffic out of L2 so the
// 1.25 MB weight-fragment set stays L2-resident — that re-fetch was 6.5 GB/dispatch)
__device__ __forceinline__ f32x4 ntld4(const float* p) {
    return __builtin_nontemporal_load((const f32x4*)p);
}

// Pre-swizzle fp32 weights into bf16 MFMA B-fragment order:
// dst[((nt*KT + kt)*64 + lane)*8 + j] = (bf16)W[nt*16 + (lane&15)][koff + kt*32 + (lane>>4)*8 + j]
__global__ void swizzle_kernel(const float* __restrict__ W, bf16* __restrict__ dst,
                               int KT, int ldw, int koff, int total) {
    int g = blockIdx.x * blockDim.x + threadIdx.x;
    if (g >= total) return;
    int lane = g & 63;
    int kt = (g >> 6) % KT;
    int nt = g / (64 * KT);
    int n = nt * 16 + (lane & 15);
    int k = kt * 32 + (lane >> 4) * 8;
    const float* src = W + (long)n * ldw + koff + k;
    f32x4 a = *(const f32x4*)src;
    f32x4 b = *(const f32x4*)(src + 4);
    bf16x8 v;
    v[0] = (bf16)a[0]; v[1] = (bf16)a[1]; v[2] = (bf16)a[2]; v[3] = (bf16)a[3];
    v[4] = (bf16)b[0]; v[5] = (bf16)b[1]; v[6] = (bf16)b[2]; v[7] = (bf16)b[3];
    *(bf16x8*)(dst + (long)g * 8) = v;
}

// stage 48 gathered fp32 rows (256 elems each) into LDS as bf16 (nontemporal reads)
__device__ __forceinline__ void gather_half(const int* __restrict__ idxp,
                                            const float* __restrict__ table,
                                            bf16* __restrict__ buf, int l0, int t) {
#pragma unroll
    for (int it = 0; it < 6; ++it) {
        int g = it * 256 + t;
        int r = g >> 5;           // 0..47
        int c = g & 31;           // 8-elem chunk within row
        int l = l0 + r;
        int li = l < L_SZ ? l : (L_SZ - 1);
        long row = idxp[li];
        const float* f = table + row * D_SZ + c * 8;
        f32x4 a = ntld4(f);
        f32x4 b2 = ntld4(f + 4);
        bf16x8 v;
        v[0] = (bf16)a[0]; v[1] = (bf16)a[1]; v[2] = (bf16)a[2]; v[3] = (bf16)a[3];
        v[4] = (bf16)b2[0]; v[5] = (bf16)b2[1]; v[6] = (bf16)b2[2]; v[7] = (bf16)b2[3];
        *(bf16x8*)(buf + r * AST + c * 8) = v;
    }
}

// GEMM pass over pre-swizzled fragments (single coalesced dwordx4 per lane),
// weight prefetch depth 2: fragments for kt+2 load while kt's 12 MFMAs issue.
template <int KTOT>
__device__ __forceinline__ void run_gemm_f(const bf16* __restrict__ abase,
                                           const bf16* __restrict__ wfrag,
                                           int koff_t, int wave, int lane,
                                           int l16, int quad, f32x4 acc[3][4]) {
    const bf16* wbase = wfrag + ((long)(wave * 4) * KTOT + koff_t) * 512 + lane * 8;
    bf16x8 b0[4], b1[4], b2[4];
#pragma unroll
    for (int nt = 0; nt < 4; ++nt) {
        b0[nt] = *(const bf16x8*)(wbase + (long)nt * KTOT * 512);
        b1[nt] = *(const bf16x8*)(wbase + ((long)nt * KTOT + 1) * 512);
    }
#pragma unroll
    for (int kt = 0; kt < 8; ++kt) {
        if (kt < 6) {
#pragma unroll
            for (int nt = 0; nt < 4; ++nt)
                b2[nt] = *(const bf16x8*)(wbase + ((long)nt * KTOT + kt + 2) * 512);
        }
        bf16x8 a[3];
#pragma unroll
        for (int mt = 0; mt < 3; ++mt)
            a[mt] = *(const bf16x8*)(abase + (mt * 16 + l16) * AST + kt * 32 + quad * 8);
#pragma unroll
        for (int nt = 0; nt < 4; ++nt)
#pragma unroll
            for (int mt = 0; mt < 3; ++mt)
                acc[mt][nt] = __builtin_amdgcn_mfma_f32_16x16x32_bf16(a[mt], b0[nt], acc[mt][nt], 0, 0, 0);
#pragma unroll
        for (int nt = 0; nt < 4; ++nt) { b0[nt] = b1[nt]; b1[nt] = b2[nt]; }
    }
}

__device__ __forceinline__ void zero_acc(f32x4 acc[3][4]) {
    f32x4 z = {0.f, 0.f, 0.f, 0.f};
#pragma unroll
    for (int mt = 0; mt < 3; ++mt)
#pragma unroll
        for (int nt = 0; nt < 4; ++nt) acc[mt][nt] = z;
}

// C-layout (col=lane&15, row=quad*4+reg) -> relu(acc+bias) -> LDS [48][AST] bf16
__device__ __forceinline__ void store_act(bf16* __restrict__ buf, f32x4 acc[3][4],
                                          const float* bias, int wave, int l16, int quad) {
#pragma unroll
    for (int mt = 0; mt < 3; ++mt)
#pragma unroll
        for (int nt = 0; nt < 4; ++nt) {
            int col = (wave * 4 + nt) * 16 + l16;
#pragma unroll
            for (int r = 0; r < 4; ++r) {
                int row = mt * 16 + quad * 4 + r;
                float v = acc[mt][nt][r] + bias[nt];
                v = v > 0.f ? v : 0.f;
                buf[row * AST + col] = (bf16)v;
            }
        }
}

__launch_bounds__(256, 3)
__global__ void ua_agg_kernel(const int* __restrict__ nodes,
                              const int* __restrict__ hua,
                              const int* __restrict__ hr,
                              const float* __restrict__ u2e,
                              const float* __restrict__ attr,
                              const float* __restrict__ r2e,
                              const bf16* __restrict__ wf,       // swizzled weights in ws
                              const float* __restrict__ b1w,
                              const float* __restrict__ b2w,
                              const float* __restrict__ att1w,   // fp32, for h1pre only
                              const float* __restrict__ a1b,
                              const float* __restrict__ a2b,
                              const float* __restrict__ att3w,
                              const float* __restrict__ a3bp,
                              float* __restrict__ out) {
    __shared__ __align__(16) bf16 abuf[MT * AST];   // union: A-half / x / h1
    __shared__ __align__(16) bf16 obuf[MT * AST];   // o (layer-2 output), kept for reduce
    __shared__ float h1pre[D_SZ];
    __shared__ float scratch[288];                  // ua_rep(256) | score_part(192)+score_row(48)+wrow(48)

    const int b = blockIdx.x;
    const int t = threadIdx.x;
    const int wave = t >> 6;
    const int lane = t & 63;
    const int l16 = t & 15;
    const int quad = (t & 63) >> 4;

    // ---- h1pre[n] = att1_b[n] + sum_k ua_rep[k] * att1_w[n][256+k]  (fp32, once per block) ----
    {
        int node = nodes[b];
        scratch[t] = __builtin_nontemporal_load(u2e + (long)node * D_SZ + t);
        __syncthreads();
        float a = a1b[t];
        const float* wr = att1w + (long)t * 512 + 256;   // 512 KB table, L2-hot: keep cached
#pragma unroll
        for (int k = 0; k < 256; k += 4) {
            f32x4 wv = *(const f32x4*)(wr + k);
            a += scratch[k] * wv[0] + scratch[k + 1] * wv[1] +
                 scratch[k + 2] * wv[2] + scratch[k + 3] * wv[3];
        }
        h1pre[t] = a;
        __syncthreads();
    }

    // per-lane column biases (col = (wave*4+nt)*16 + l16)
    float bias1[4], bias2[4], bias3[4], bias4[4], a3[4];
#pragma unroll
    for (int nt = 0; nt < 4; ++nt) {
        int col = (wave * 4 + nt) * 16 + l16;
        bias1[nt] = b1w[col];
        bias2[nt] = b2w[col];
        bias3[nt] = h1pre[col];      // includes att1_b
        bias4[nt] = a2b[col];
        a3[nt] = att3w[col];
    }
    const float a3bias = a3bp[0];

    const int* huab = hua + (long)b * L_SZ;
    const int* hrb = hr + (long)b * L_SZ;

    float accv = 0.f, srun = 0.f, mrun = -INFINITY;
    float* score_part = scratch;        // [4][48]
    float* score_row = scratch + 192;   // [48]
    float* wrow = scratch + 240;        // [48]

    for (int tile = 0; tile < NTILE; ++tile) {
        const int l0 = tile * MT;
        f32x4 acc[3][4];
        zero_acc(acc);

        // ---- layer 1 (K=512: e_ua half then e_r half) ----
        gather_half(huab, attr, abuf, l0, t);
        __syncthreads();
        run_gemm_f<16>(abuf, wf + W1F_OFF, 0, wave, lane, l16, quad, acc);
        __syncthreads();
        gather_half(hrb, r2e, abuf, l0, t);
        __syncthreads();
        run_gemm_f<16>(abuf, wf + W1F_OFF, 8, wave, lane, l16, quad, acc);
        __syncthreads();
        store_act(abuf, acc, bias1, wave, l16, quad);   // x -> abuf
        __syncthreads();

        // ---- layer 2: o = relu(W2 x + b2) ----
        zero_acc(acc);
        run_gemm_f<8>(abuf, wf + W2F_OFF, 0, wave, lane, l16, quad, acc);
        store_act(obuf, acc, bias2, wave, l16, quad);   // o -> obuf
        __syncthreads();

        // ---- layer 3: h1 = relu(att1[:, :256] o + h1pre) ----
        zero_acc(acc);
        run_gemm_f<8>(obuf, wf + A1F_OFF, 0, wave, lane, l16, quad, acc);
        store_act(abuf, acc, bias3, wave, l16, quad);   // h1 -> abuf
        __syncthreads();

        // ---- layer 4 + score ----
        zero_acc(acc);
        run_gemm_f<8>(abuf, wf + A2F_OFF, 0, wave, lane, l16, quad, acc);

        float p[3][4];
#pragma unroll
        for (int mt = 0; mt < 3; ++mt)
#pragma unroll
            for (int r = 0; r < 4; ++r) {
                float s = 0.f;
#pragma unroll
                for (int nt = 0; nt < 4; ++nt) {
                    float h = acc[mt][nt][r] + bias4[nt];
                    h = h > 0.f ? h : 0.f;
                    s += h * a3[nt];
                }
                p[mt][r] = s;
            }
        // sum over the 16 l16-lanes within each quad group (width-16 xor shuffle)
#pragma unroll
        for (int off = 1; off < 16; off <<= 1)
#pragma unroll
            for (int mt = 0; mt < 3; ++mt)
#pragma unroll
                for (int r = 0; r < 4; ++r) p[mt][r] += __shfl_xor(p[mt][r], off, 16);
        if (l16 == 0) {
#pragma unroll
            for (int mt = 0; mt < 3; ++mt)
#pragma unroll
                for (int r = 0; r < 4; ++r)
                    score_part[wave * 48 + mt * 16 + quad * 4 + r] = p[mt][r];
        }
        __syncthreads();
        if (t < MT) {
            float s = score_part[t] + score_part[48 + t] + score_part[96 + t] +
                      score_part[144 + t] + a3bias;
            score_row[t] = (l0 + t < L_SZ) ? s : -INFINITY;
        }
        __syncthreads();

        // ---- online softmax + weighted accumulate (thread t owns output column t) ----
        float tm = -INFINITY;
        for (int r = 0; r < MT; ++r) tm = fmaxf(tm, score_row[r]);
        float nm = fmaxf(mrun, tm);
        float factor = __expf(mrun - nm);   // 0 on first tile (mrun=-inf)
        if (t < MT) wrow[t] = __expf(score_row[t] - nm);  // 0 for masked rows
        __syncthreads();
        float wsum = 0.f, av = 0.f;
#pragma unroll 8
        for (int r = 0; r < MT; ++r) {
            float w = wrow[r];
            wsum += w;
            av += w * (float)obuf[r * AST + t];
        }
        accv = accv * factor + av;
        srun = srun * factor + wsum;
        mrun = nm;
        __syncthreads();
    }

    __builtin_nontemporal_store(accv / srun, out + (long)b * D_SZ + t);
}

extern "C" void kernel_launch(void* const* d_in, const int* in_sizes, int n_in,
                              void* d_out, int out_size, void* d_ws, size_t ws_size,
                              hipStream_t stream) {
    const int* nodes = (const int*)d_in[0];
    const int* hua = (const int*)d_in[1];
    const int* hr = (const int*)d_in[2];
    // d_in[3] history_uat unused by the reference
    const float* u2e = (const float*)d_in[4];
    const float* attr = (const float*)d_in[5];
    const float* r2e = (const float*)d_in[6];
    const float* w1 = (const float*)d_in[7];
    const float* b1 = (const float*)d_in[8];
    const float* w2 = (const float*)d_in[9];
    const float* b2 = (const float*)d_in[10];
    const float* a1w = (const float*)d_in[11];
    const float* a1b = (const float*)d_in[12];
    const float* a2w = (const float*)d_in[13];
    const float* a2b = (const float*)d_in[14];
    const float* a3w = (const float*)d_in[15];
    const float* a3b = (const float*)d_in[16];
    bf16* wsb = (bf16*)d_ws;

    // one-time (per launch, idempotent) fp32 -> bf16 fragment swizzle of all weights
    swizzle_kernel<<<64, 256, 0, stream>>>(w1, wsb + W1F_OFF, 16, 512, 0, 16384);
    swizzle_kernel<<<32, 256, 0, stream>>>(w2, wsb + W2F_OFF, 8, 256, 0, 8192);
    swizzle_kernel<<<32, 256, 0, stream>>>(a1w, wsb + A1F_OFF, 8, 512, 0, 8192);
    swizzle_kernel<<<32, 256, 0, stream>>>(a2w, wsb + A2F_OFF, 8, 256, 0, 8192);

    ua_agg_kernel<<<B_SZ, 256, 0, stream>>>(nodes, hua, hr, u2e, attr, r2e,
                                            wsb, b1, b2, a1w, a1b, a2b,
                                            a3w, a3b, (float*)d_out);
}

// Round 7
// 695.233 us; speedup vs baseline: 3.0591x; 3.0591x over previous
//
#include <hip/hip_runtime.h>
#include <hip/hip_bf16.h>

typedef __bf16 bf16;
typedef __bf16 bf16x8 __attribute__((ext_vector_type(8)));
typedef float f32x4 __attribute__((ext_vector_type(4)));

#define L_SZ 200
#define D_SZ 256
#define NROWS (2048 * 200)
#define MB 128           // rows per block in layer-major kernels
#define AST 264          // LDS activation row stride (bf16 elems)

// ---- ws layout (byte offsets) ----
#define WS_W1F 0u            // w1   swizzled bf16 256x512 -> 262144 B
#define WS_W2F 262144u       // w2   256x256 -> 131072
#define WS_A1L 393216u       // att1[:, :256] -> 131072
#define WS_A1H 524288u       // att1[:, 256:] -> 131072
#define WS_A2F 655360u       // att2 256x256 -> 131072
#define WS_H1P 786432u       // h1pre fp32 [2048][256] -> 2097152
#define WS_SCR 2883584u      // scores fp32 [409600] -> 1638400
#define WS_O   4521984u      // o bf16 [409600][256] -> 209715200
#define WS_NEED (WS_O + 209715200u)

// ---------------- weight pre-swizzle (fp32 -> bf16 MFMA B-fragments) ----------------
// dst frag g=((nt*KT+kt)*64+lane): elems g*8.. = W[nt*16+(lane&15)][koff+kt*32+(lane>>4)*8 ..+7]
__global__ void swizzle_kernel(const float* __restrict__ W, bf16* __restrict__ dst,
                               int KT, int ldw, int koff, int total) {
    int g = blockIdx.x * blockDim.x + threadIdx.x;
    if (g >= total) return;
    int lane = g & 63;
    int kt = (g >> 6) % KT;
    int nt = g / (64 * KT);
    int n = nt * 16 + (lane & 15);
    int k = kt * 32 + (lane >> 4) * 8;
    const float* src = W + (long)n * ldw + koff + k;
    f32x4 a = *(const f32x4*)src;
    f32x4 b = *(const f32x4*)(src + 4);
    bf16x8 v;
    v[0] = (bf16)a[0]; v[1] = (bf16)a[1]; v[2] = (bf16)a[2]; v[3] = (bf16)a[3];
    v[4] = (bf16)b[0]; v[5] = (bf16)b[1]; v[6] = (bf16)b[2]; v[7] = (bf16)b[3];
    *(bf16x8*)(dst + (long)g * 8) = v;
}

// ---------------- shared device helpers ----------------
// stage MB fp32 rows (indices in LDS) into LDS as bf16 [MB][AST]
__device__ __forceinline__ void stage_rows(const int* __restrict__ idxl,
                                           const float* __restrict__ table,
                                           bf16* __restrict__ buf, int t) {
#pragma unroll
    for (int it = 0; it < 16; ++it) {
        int g = it * 256 + t;
        int r = g >> 5;          // 0..127
        int c = g & 31;          // 8-float chunk
        long row = idxl[r];
        const float* f = table + row * D_SZ + c * 8;
        f32x4 a = *(const f32x4*)f;
        f32x4 b = *(const f32x4*)(f + 4);
        bf16x8 v;
        v[0] = (bf16)a[0]; v[1] = (bf16)a[1]; v[2] = (bf16)a[2]; v[3] = (bf16)a[3];
        v[4] = (bf16)b[0]; v[5] = (bf16)b[1]; v[6] = (bf16)b[2]; v[7] = (bf16)b[3];
        *(bf16x8*)(buf + r * AST + c * 8) = v;
    }
}

// GEMM: A[128][256] from LDS, B fragments from ws (prefetch depth 1), acc 8x4
template <int KTOT>
__device__ __forceinline__ void gemm8(const bf16* __restrict__ abase,
                                      const bf16* __restrict__ wfrag, int koff_t,
                                      int wave, int lane, int l16, int quad,
                                      f32x4 acc[8][4]) {
    const bf16* wbase = wfrag + ((long)(wave * 4) * KTOT + koff_t) * 512 + lane * 8;
    bf16x8 bc[4], bn[4];
#pragma unroll
    for (int nt = 0; nt < 4; ++nt)
        bc[nt] = *(const bf16x8*)(wbase + (long)nt * KTOT * 512);
#pragma unroll
    for (int kt = 0; kt < 8; ++kt) {
        if (kt < 7) {
#pragma unroll
            for (int nt = 0; nt < 4; ++nt)
                bn[nt] = *(const bf16x8*)(wbase + ((long)nt * KTOT + kt + 1) * 512);
        }
        bf16x8 a[8];
#pragma unroll
        for (int mt = 0; mt < 8; ++mt)
            a[mt] = *(const bf16x8*)(abase + (mt * 16 + l16) * AST + kt * 32 + quad * 8);
#pragma unroll
        for (int nt = 0; nt < 4; ++nt)
#pragma unroll
            for (int mt = 0; mt < 8; ++mt)
                acc[mt][nt] = __builtin_amdgcn_mfma_f32_16x16x32_bf16(a[mt], bc[nt], acc[mt][nt], 0, 0, 0);
#pragma unroll
        for (int nt = 0; nt < 4; ++nt) bc[nt] = bn[nt];
    }
}

__device__ __forceinline__ void zero8(f32x4 acc[8][4]) {
    f32x4 z = {0.f, 0.f, 0.f, 0.f};
#pragma unroll
    for (int mt = 0; mt < 8; ++mt)
#pragma unroll
        for (int nt = 0; nt < 4; ++nt) acc[mt][nt] = z;
}

__device__ __forceinline__ void store_act8(bf16* __restrict__ buf, f32x4 acc[8][4],
                                           const float* bias, int wave, int l16, int quad) {
#pragma unroll
    for (int mt = 0; mt < 8; ++mt)
#pragma unroll
        for (int nt = 0; nt < 4; ++nt) {
            int col = (wave * 4 + nt) * 16 + l16;
#pragma unroll
            for (int r = 0; r < 4; ++r) {
                int row = mt * 16 + quad * 4 + r;
                float v = acc[mt][nt][r] + bias[nt];
                v = v > 0.f ? v : 0.f;
                buf[row * AST + col] = (bf16)v;
            }
        }
}

// ---------------- K0: h1pre[b][n] = a1b[n] + u2e[nodes[b]] . att1w[n][256:] ----------------
__launch_bounds__(256, 2)
__global__ void k0_h1pre(const int* __restrict__ nodes, const float* __restrict__ u2e,
                         const bf16* __restrict__ wf_a1h, const float* __restrict__ a1b,
                         float* __restrict__ h1p) {
    __shared__ __align__(16) bf16 abuf[MB * AST];
    __shared__ int idxl[MB];
    const int blk = blockIdx.x, t = threadIdx.x;
    const int wave = t >> 6, lane = t & 63, l16 = t & 15, quad = (t & 63) >> 4;
    if (t < MB) idxl[t] = nodes[blk * MB + t];
    __syncthreads();
    stage_rows(idxl, u2e, abuf, t);
    __syncthreads();
    f32x4 acc[8][4];
    zero8(acc);
    gemm8<8>(abuf, wf_a1h, 0, wave, lane, l16, quad, acc);
#pragma unroll
    for (int nt = 0; nt < 4; ++nt) {
        int col = (wave * 4 + nt) * 16 + l16;
        float ab = a1b[col];
#pragma unroll
        for (int mt = 0; mt < 8; ++mt)
#pragma unroll
            for (int r = 0; r < 4; ++r) {
                int row = mt * 16 + quad * 4 + r;
                h1p[(long)(blk * MB + row) * D_SZ + col] = acc[mt][nt][r] + ab;
            }
    }
}

// ---------------- K1: gather + layer1 + layer2 -> o ----------------
__launch_bounds__(256, 2)
__global__ void k1_gemm12(const int* __restrict__ hua, const int* __restrict__ hr,
                          const float* __restrict__ attr, const float* __restrict__ r2e,
                          const bf16* __restrict__ wf_w1, const bf16* __restrict__ wf_w2,
                          const float* __restrict__ b1w, const float* __restrict__ b2w,
                          bf16* __restrict__ o_out) {
    __shared__ __align__(16) bf16 abuf[MB * AST];
    __shared__ int idx_ua[MB], idx_r[MB];
    const int blk = blockIdx.x, t = threadIdx.x;
    const int wave = t >> 6, lane = t & 63, l16 = t & 15, quad = (t & 63) >> 4;
    const long r0 = (long)blk * MB;     // flat (b,l) row: hua/hr are [2048*200] flat
    if (t < MB) { idx_ua[t] = hua[r0 + t]; idx_r[t] = hr[r0 + t]; }
    __syncthreads();

    float bias1[4], bias2[4];
#pragma unroll
    for (int nt = 0; nt < 4; ++nt) {
        int col = (wave * 4 + nt) * 16 + l16;
        bias1[nt] = b1w[col];
        bias2[nt] = b2w[col];
    }

    f32x4 acc[8][4];
    zero8(acc);
    stage_rows(idx_ua, attr, abuf, t);
    __syncthreads();
    gemm8<16>(abuf, wf_w1, 0, wave, lane, l16, quad, acc);
    __syncthreads();
    stage_rows(idx_r, r2e, abuf, t);
    __syncthreads();
    gemm8<16>(abuf, wf_w1, 8, wave, lane, l16, quad, acc);
    __syncthreads();
    store_act8(abuf, acc, bias1, wave, l16, quad);   // x -> abuf (in place, post-barrier)
    __syncthreads();
    zero8(acc);
    gemm8<8>(abuf, wf_w2, 0, wave, lane, l16, quad, acc);
    __syncthreads();                                  // all waves done reading x
    store_act8(abuf, acc, bias2, wave, l16, quad);   // o -> abuf
    __syncthreads();
    // coalesced o tile -> global (row-major bf16, unpadded)
#pragma unroll
    for (int it = 0; it < 16; ++it) {
        int g = it * 256 + t;
        int r = g >> 5, c = g & 31;
        *(bf16x8*)(o_out + (r0 + r) * D_SZ + c * 8) = *(const bf16x8*)(abuf + r * AST + c * 8);
    }
}

// ---------------- K2: layer3 + layer4 + score ----------------
__launch_bounds__(256, 2)
__global__ void k2_gemm34(const bf16* __restrict__ o_in,
                          const bf16* __restrict__ wf_a1l, const bf16* __restrict__ wf_a2f,
                          const float* __restrict__ h1p, const float* __restrict__ a2b,
                          const float* __restrict__ a3w, float* __restrict__ scores) {
    __shared__ __align__(16) bf16 abuf[MB * AST];
    __shared__ float hp[2][D_SZ];
    __shared__ float spart[4][MB];
    const int blk = blockIdx.x, t = threadIdx.x;
    const int wave = t >> 6, lane = t & 63, l16 = t & 15, quad = (t & 63) >> 4;
    const long r0 = (long)blk * MB;
    const int b0 = (int)(r0 / L_SZ);
    const int b1 = min(b0 + 1, 2047);
    const long bsplit = (long)(b0 + 1) * L_SZ;
    hp[0][t] = h1p[(long)b0 * D_SZ + t];
    hp[1][t] = h1p[(long)b1 * D_SZ + t];
    // stage o tile into LDS
#pragma unroll
    for (int it = 0; it < 16; ++it) {
        int g = it * 256 + t;
        int r = g >> 5, c = g & 31;
        *(bf16x8*)(abuf + r * AST + c * 8) = *(const bf16x8*)(o_in + (r0 + r) * D_SZ + c * 8);
    }
    __syncthreads();

    f32x4 acc[8][4];
    zero8(acc);
    gemm8<8>(abuf, wf_a1l, 0, wave, lane, l16, quad, acc);
    __syncthreads();   // all reads of o done
    // h1 = relu(acc + h1pre[b(row)][col]) -> abuf
#pragma unroll
    for (int nt = 0; nt < 4; ++nt) {
        int col = (wave * 4 + nt) * 16 + l16;
#pragma unroll
        for (int mt = 0; mt < 8; ++mt)
#pragma unroll
            for (int r = 0; r < 4; ++r) {
                int row = mt * 16 + quad * 4 + r;
                float bias = ((r0 + row) >= bsplit) ? hp[1][col] : hp[0][col];
                float v = acc[mt][nt][r] + bias;
                v = v > 0.f ? v : 0.f;
                abuf[row * AST + col] = (bf16)v;
            }
    }
    __syncthreads();
    zero8(acc);
    gemm8<8>(abuf, wf_a2f, 0, wave, lane, l16, quad, acc);

    float bias4[4], a3[4];
#pragma unroll
    for (int nt = 0; nt < 4; ++nt) {
        int col = (wave * 4 + nt) * 16 + l16;
        bias4[nt] = a2b[col];
        a3[nt] = a3w[col];
    }
    float p[8][4];
#pragma unroll
    for (int mt = 0; mt < 8; ++mt)
#pragma unroll
        for (int r = 0; r < 4; ++r) {
            float s = 0.f;
#pragma unroll
            for (int nt = 0; nt < 4; ++nt) {
                float h = acc[mt][nt][r] + bias4[nt];
                h = h > 0.f ? h : 0.f;
                s += h * a3[nt];
            }
            p[mt][r] = s;
        }
#pragma unroll
    for (int off = 1; off < 16; off <<= 1)
#pragma unroll
        for (int mt = 0; mt < 8; ++mt)
#pragma unroll
            for (int r = 0; r < 4; ++r) p[mt][r] += __shfl_xor(p[mt][r], off, 16);
    if (l16 == 0) {
#pragma unroll
        for (int mt = 0; mt < 8; ++mt)
#pragma unroll
            for (int r = 0; r < 4; ++r)
                spart[wave][mt * 16 + quad * 4 + r] = p[mt][r];
    }
    __syncthreads();
    if (t < MB)   // att3_b omitted: constant shift is softmax-invariant
        scores[r0 + t] = spart[0][t] + spart[1][t] + spart[2][t] + spart[3][t];
}

// ---------------- K5: exact softmax over L + weighted reduce ----------------
__global__ void k5_reduce(const float* __restrict__ scores, const bf16* __restrict__ o_in,
                          float* __restrict__ out) {
    __shared__ float red[256];
    __shared__ float watt[256];
    const int b = blockIdx.x, t = threadIdx.x;
    float s = (t < L_SZ) ? scores[(long)b * L_SZ + t] : -INFINITY;
    red[t] = s;
    __syncthreads();
    for (int off = 128; off > 0; off >>= 1) {
        if (t < off) red[t] = fmaxf(red[t], red[t + off]);
        __syncthreads();
    }
    float mx = red[0];
    __syncthreads();
    float w = (t < L_SZ) ? __expf(s - mx) : 0.f;
    watt[t] = w;
    red[t] = w;
    __syncthreads();
    for (int off = 128; off > 0; off >>= 1) {
        if (t < off) red[t] += red[t + off];
        __syncthreads();
    }
    float inv = 1.f / red[0];
    float accv = 0.f;
    const bf16* ob = o_in + (long)b * L_SZ * D_SZ + t;
#pragma unroll 4
    for (int l = 0; l < L_SZ; ++l) accv += watt[l] * (float)ob[(long)l * D_SZ];
    out[(long)b * D_SZ + t] = accv * inv;
}

// ================= fallback fused kernel (R5 structure) for small ws =================
__device__ __forceinline__ void gather_half_f(const int* __restrict__ idxp,
                                              const float* __restrict__ table,
                                              bf16* __restrict__ buf, int l0, int t) {
#pragma unroll
    for (int it = 0; it < 6; ++it) {
        int g = it * 256 + t;
        int r = g >> 5, c = g & 31;
        int l = l0 + r;
        int li = l < L_SZ ? l : (L_SZ - 1);
        long row = idxp[li];
        const float* f = table + row * D_SZ + c * 8;
        f32x4 a = *(const f32x4*)f;
        f32x4 b2 = *(const f32x4*)(f + 4);
        bf16x8 v;
        v[0] = (bf16)a[0]; v[1] = (bf16)a[1]; v[2] = (bf16)a[2]; v[3] = (bf16)a[3];
        v[4] = (bf16)b2[0]; v[5] = (bf16)b2[1]; v[6] = (bf16)b2[2]; v[7] = (bf16)b2[3];
        *(bf16x8*)(buf + r * AST + c * 8) = v;
    }
}

template <int KTOT>
__device__ __forceinline__ void run_gemm3(const bf16* __restrict__ abase,
                                          const bf16* __restrict__ wfrag, int koff_t,
                                          int wave, int lane, int l16, int quad,
                                          f32x4 acc[3][4]) {
    const bf16* wbase = wfrag + ((long)(wave * 4) * KTOT + koff_t) * 512 + lane * 8;
    bf16x8 bc[4], bn[4];
#pragma unroll
    for (int nt = 0; nt < 4; ++nt)
        bc[nt] = *(const bf16x8*)(wbase + (long)nt * KTOT * 512);
#pragma unroll
    for (int kt = 0; kt < 8; ++kt) {
        if (kt < 7) {
#pragma unroll
            for (int nt = 0; nt < 4; ++nt)
                bn[nt] = *(const bf16x8*)(wbase + ((long)nt * KTOT + kt + 1) * 512);
        }
        bf16x8 a[3];
#pragma unroll
        for (int mt = 0; mt < 3; ++mt)
            a[mt] = *(const bf16x8*)(abase + (mt * 16 + l16) * AST + kt * 32 + quad * 8);
#pragma unroll
        for (int nt = 0; nt < 4; ++nt)
#pragma unroll
            for (int mt = 0; mt < 3; ++mt)
                acc[mt][nt] = __builtin_amdgcn_mfma_f32_16x16x32_bf16(a[mt], bc[nt], acc[mt][nt], 0, 0, 0);
#pragma unroll
        for (int nt = 0; nt < 4; ++nt) bc[nt] = bn[nt];
    }
}

__launch_bounds__(256, 3)
__global__ void ua_fused(const int* __restrict__ nodes, const int* __restrict__ hua,
                         const int* __restrict__ hr, const float* __restrict__ u2e,
                         const float* __restrict__ attr, const float* __restrict__ r2e,
                         const bf16* __restrict__ wf1, const bf16* __restrict__ wf2,
                         const bf16* __restrict__ wfa1, const bf16* __restrict__ wfa2,
                         const float* __restrict__ b1w, const float* __restrict__ b2w,
                         const float* __restrict__ att1w, const float* __restrict__ a1b,
                         const float* __restrict__ a2b, const float* __restrict__ att3w,
                         const float* __restrict__ a3bp, float* __restrict__ out) {
    __shared__ __align__(16) bf16 abuf[48 * AST];
    __shared__ __align__(16) bf16 obuf[48 * AST];
    __shared__ float h1pre[D_SZ];
    __shared__ float scratch[288];
    const int b = blockIdx.x, t = threadIdx.x;
    const int wave = t >> 6, lane = t & 63, l16 = t & 15, quad = (t & 63) >> 4;
    {
        int node = nodes[b];
        scratch[t] = u2e[(long)node * D_SZ + t];
        __syncthreads();
        float a = a1b[t];
        const float* wr = att1w + (long)t * 512 + 256;
#pragma unroll
        for (int k = 0; k < 256; k += 4) {
            f32x4 wv = *(const f32x4*)(wr + k);
            a += scratch[k] * wv[0] + scratch[k + 1] * wv[1] +
                 scratch[k + 2] * wv[2] + scratch[k + 3] * wv[3];
        }
        h1pre[t] = a;
        __syncthreads();
    }
    float bias1[4], bias2[4], bias3[4], bias4[4], a3[4];
#pragma unroll
    for (int nt = 0; nt < 4; ++nt) {
        int col = (wave * 4 + nt) * 16 + l16;
        bias1[nt] = b1w[col]; bias2[nt] = b2w[col]; bias3[nt] = h1pre[col];
        bias4[nt] = a2b[col]; a3[nt] = att3w[col];
    }
    const float a3bias = a3bp[0];
    const int* huab = hua + (long)b * L_SZ;
    const int* hrb = hr + (long)b * L_SZ;
    float accv = 0.f, srun = 0.f, mrun = -INFINITY;
    float* score_part = scratch;
    float* score_row = scratch + 192;
    float* wrow = scratch + 240;
    auto st3 = [&](bf16* buf, f32x4 acc[3][4], const float* bias) {
#pragma unroll
        for (int mt = 0; mt < 3; ++mt)
#pragma unroll
            for (int nt = 0; nt < 4; ++nt) {
                int col = (wave * 4 + nt) * 16 + l16;
#pragma unroll
                for (int r = 0; r < 4; ++r) {
                    float v = acc[mt][nt][r] + bias[nt];
                    v = v > 0.f ? v : 0.f;
                    buf[(mt * 16 + quad * 4 + r) * AST + col] = (bf16)v;
                }
            }
    };
    for (int tile = 0; tile < 5; ++tile) {
        const int l0 = tile * 48;
        f32x4 acc[3][4];
        f32x4 z = {0.f, 0.f, 0.f, 0.f};
#pragma unroll
        for (int mt = 0; mt < 3; ++mt)
#pragma unroll
            for (int nt = 0; nt < 4; ++nt) acc[mt][nt] = z;
        gather_half_f(huab, attr, abuf, l0, t);
        __syncthreads();
        run_gemm3<16>(abuf, wf1, 0, wave, lane, l16, quad, acc);
        __syncthreads();
        gather_half_f(hrb, r2e, abuf, l0, t);
        __syncthreads();
        run_gemm3<16>(abuf, wf1, 8, wave, lane, l16, quad, acc);
        __syncthreads();
        st3(abuf, acc, bias1);
        __syncthreads();
#pragma unroll
        for (int mt = 0; mt < 3; ++mt)
#pragma unroll
            for (int nt = 0; nt < 4; ++nt) acc[mt][nt] = z;
        run_gemm3<8>(abuf, wf2, 0, wave, lane, l16, quad, acc);
        st3(obuf, acc, bias2);
        __syncthreads();
#pragma unroll
        for (int mt = 0; mt < 3; ++mt)
#pragma unroll
            for (int nt = 0; nt < 4; ++nt) acc[mt][nt] = z;
        run_gemm3<8>(obuf, wfa1, 0, wave, lane, l16, quad, acc);
        st3(abuf, acc, bias3);
        __syncthreads();
#pragma unroll
        for (int mt = 0; mt < 3; ++mt)
#pragma unroll
            for (int nt = 0; nt < 4; ++nt) acc[mt][nt] = z;
        run_gemm3<8>(abuf, wfa2, 0, wave, lane, l16, quad, acc);
        float p[3][4];
#pragma unroll
        for (int mt = 0; mt < 3; ++mt)
#pragma unroll
            for (int r = 0; r < 4; ++r) {
                float s = 0.f;
#pragma unroll
                for (int nt = 0; nt < 4; ++nt) {
                    float h = acc[mt][nt][r] + bias4[nt];
                    h = h > 0.f ? h : 0.f;
                    s += h * a3[nt];
                }
                p[mt][r] = s;
            }
#pragma unroll
        for (int off = 1; off < 16; off <<= 1)
#pragma unroll
            for (int mt = 0; mt < 3; ++mt)
#pragma unroll
                for (int r = 0; r < 4; ++r) p[mt][r] += __shfl_xor(p[mt][r], off, 16);
        if (l16 == 0) {
#pragma unroll
            for (int mt = 0; mt < 3; ++mt)
#pragma unroll
                for (int r = 0; r < 4; ++r)
                    score_part[wave * 48 + mt * 16 + quad * 4 + r] = p[mt][r];
        }
        __syncthreads();
        if (t < 48) {
            float s = score_part[t] + score_part[48 + t] + score_part[96 + t] +
                      score_part[144 + t] + a3bias;
            score_row[t] = (l0 + t < L_SZ) ? s : -INFINITY;
        }
        __syncthreads();
        float tm = -INFINITY;
        for (int r = 0; r < 48; ++r) tm = fmaxf(tm, score_row[r]);
        float nm = fmaxf(mrun, tm);
        float factor = __expf(mrun - nm);
        if (t < 48) wrow[t] = __expf(score_row[t] - nm);
        __syncthreads();
        float wsum = 0.f, av = 0.f;
#pragma unroll 8
        for (int r = 0; r < 48; ++r) {
            float w = wrow[r];
            wsum += w;
            av += w * (float)obuf[r * AST + t];
        }
        accv = accv * factor + av;
        srun = srun * factor + wsum;
        mrun = nm;
        __syncthreads();
    }
    out[(long)b * D_SZ + t] = accv / srun;
}

extern "C" void kernel_launch(void* const* d_in, const int* in_sizes, int n_in,
                              void* d_out, int out_size, void* d_ws, size_t ws_size,
                              hipStream_t stream) {
    const int* nodes = (const int*)d_in[0];
    const int* hua = (const int*)d_in[1];
    const int* hr = (const int*)d_in[2];
    // d_in[3] history_uat unused
    const float* u2e = (const float*)d_in[4];
    const float* attr = (const float*)d_in[5];
    const float* r2e = (const float*)d_in[6];
    const float* w1 = (const float*)d_in[7];
    const float* b1 = (const float*)d_in[8];
    const float* w2 = (const float*)d_in[9];
    const float* b2 = (const float*)d_in[10];
    const float* a1w = (const float*)d_in[11];
    const float* a1b = (const float*)d_in[12];
    const float* a2w = (const float*)d_in[13];
    const float* a2b = (const float*)d_in[14];
    const float* a3w = (const float*)d_in[15];
    const float* a3b = (const float*)d_in[16];
    char* ws = (char*)d_ws;
    bf16* wf_w1 = (bf16*)(ws + WS_W1F);
    bf16* wf_w2 = (bf16*)(ws + WS_W2F);
    bf16* wf_a1l = (bf16*)(ws + WS_A1L);
    bf16* wf_a1h = (bf16*)(ws + WS_A1H);
    bf16* wf_a2f = (bf16*)(ws + WS_A2F);

    swizzle_kernel<<<64, 256, 0, stream>>>(w1, wf_w1, 16, 512, 0, 16384);
    swizzle_kernel<<<32, 256, 0, stream>>>(w2, wf_w2, 8, 256, 0, 8192);
    swizzle_kernel<<<32, 256, 0, stream>>>(a1w, wf_a1l, 8, 512, 0, 8192);
    swizzle_kernel<<<32, 256, 0, stream>>>(a2w, wf_a2f, 8, 256, 0, 8192);

    if (ws_size >= (size_t)WS_NEED) {
        float* h1p = (float*)(ws + WS_H1P);
        float* scores = (float*)(ws + WS_SCR);
        bf16* obuf = (bf16*)(ws + WS_O);
        swizzle_kernel<<<32, 256, 0, stream>>>(a1w, wf_a1h, 8, 512, 256, 8192);
        k0_h1pre<<<2048 / MB, 256, 0, stream>>>(nodes, u2e, wf_a1h, a1b, h1p);
        k1_gemm12<<<NROWS / MB, 256, 0, stream>>>(hua, hr, attr, r2e, wf_w1, wf_w2,
                                                  b1, b2, obuf);
        k2_gemm34<<<NROWS / MB, 256, 0, stream>>>(obuf, wf_a1l, wf_a2f, h1p, a2b,
                                                  a3w, scores);
        k5_reduce<<<2048, 256, 0, stream>>>(scores, obuf, (float*)d_out);
    } else {
        ua_fused<<<2048, 256, 0, stream>>>(nodes, hua, hr, u2e, attr, r2e,
                                           wf_w1, wf_w2, wf_a1l, wf_a2f,
                                           b1, b2, a1w, a1b, a2b, a3w, a3b,
                                           (float*)d_out);
    }
}